// Round 1
// baseline (645.091 us; speedup 1.0000x reference)
//
#include <hip/hip_runtime.h>

typedef float fx4 __attribute__((ext_vector_type(4)));
typedef __bf16 bf16x8 __attribute__((ext_vector_type(8)));
typedef unsigned short ushort8 __attribute__((ext_vector_type(8)));

#define MFMA16(a, b, c) __builtin_amdgcn_mfma_f32_16x16x32_bf16((a), (b), (c), 0, 0, 0)

__device__ __forceinline__ unsigned short f2bf(float f) {
  unsigned int u = __float_as_uint(f);
  return (unsigned short)((u + 0x7FFFu + ((u >> 16) & 1u)) >> 16);
}

__device__ __forceinline__ ushort8 pack8(fx4 a, fx4 b) {
  ushort8 v;
  v[0] = f2bf(a[0]); v[1] = f2bf(a[1]); v[2] = f2bf(a[2]); v[3] = f2bf(a[3]);
  v[4] = f2bf(b[0]); v[5] = f2bf(b[1]); v[6] = f2bf(b[2]); v[7] = f2bf(b[3]);
  return v;
}

// ---------- PE table + zero stats ----------
__global__ void k_pe(float* __restrict__ pe, float* __restrict__ sums, float* __restrict__ sqs) {
  int idx = blockIdx.x * 256 + threadIdx.x;  // < 197*768 = 151296 exactly
  int s = idx / 768;
  int j = idx - s * 768;
  int jj = j & ~1;
  float ang = (float)s * expf((float)jj * (-9.210340371976184f / 768.0f));
  pe[idx] = (j & 1) ? cosf(ang) : sinf(ang);
  if (blockIdx.x == 0 && threadIdx.x < 128) {
    sums[threadIdx.x] = 0.f;
    sqs[threadIdx.x] = 0.f;
  }
}

// ---------- W_map fp32 -> bf16 ----------
__global__ void k_cvtw(const float* __restrict__ W, unsigned short* __restrict__ wbf) {
  int i = (blockIdx.x * 256 + threadIdx.x) * 8;  // 288 blocks * 256 * 8 = 589824 exactly
  const fx4* p = (const fx4*)(W + i);
  *(ushort8*)(wbf + i) = pack8(p[0], p[1]);
}

// ---------- tokens = patches @ W_map^T + b_map + PE; also LN partial stats ----------
// grid (6 n-tiles, 196 m-tiles), 256 thr. M=25088=196*128, N=768=6*128, K=768.
__global__ __launch_bounds__(256) void k_tokens(
    const float* __restrict__ img, const unsigned short* __restrict__ wbf,
    const float* __restrict__ bmap, const float* __restrict__ pe,
    float* __restrict__ out, float* __restrict__ sums, float* __restrict__ sqs) {
  __shared__ __align__(16) unsigned short As[128][40];  // +8 pad breaks pow2 stride
  __shared__ __align__(16) unsigned short Bs[128][40];
  const int tid = threadIdx.x;
  const int n0 = blockIdx.x * 128;
  const int m0 = blockIdx.y * 128;
  const int lane = tid & 63;
  const int w = tid >> 6;
  const int quad = lane >> 4, l16 = lane & 15;
  const int m_off = (w & 1) * 64, n_off = (w >> 1) * 64;

  fx4 acc[4][4];
#pragma unroll
  for (int i = 0; i < 4; i++)
#pragma unroll
    for (int j = 0; j < 4; j++) acc[i][j] = (fx4){0.f, 0.f, 0.f, 0.f};

  const int srow = tid >> 2;        // 0..63
  const int skc = (tid & 3) * 8;    // 0,8,16,24

  for (int k0 = 0; k0 < 768; k0 += 32) {
    __syncthreads();
#pragma unroll
    for (int rr = 0; rr < 2; rr++) {
      const int r = srow + rr * 64;
      const fx4* pa = (const fx4*)(img + (size_t)(m0 + r) * 768 + k0 + skc);
      *(ushort8*)&As[r][skc] = pack8(pa[0], pa[1]);
      *(ushort8*)&Bs[r][skc] = *(const ushort8*)(wbf + (size_t)(n0 + r) * 768 + k0 + skc);
    }
    __syncthreads();
    bf16x8 a[4], b[4];
#pragma unroll
    for (int mt = 0; mt < 4; mt++) a[mt] = *(const bf16x8*)&As[m_off + mt * 16 + l16][quad * 8];
#pragma unroll
    for (int nt = 0; nt < 4; nt++) b[nt] = *(const bf16x8*)&Bs[n_off + nt * 16 + l16][quad * 8];
#pragma unroll
    for (int mt = 0; mt < 4; mt++)
#pragma unroll
      for (int nt = 0; nt < 4; nt++) acc[mt][nt] = MFMA16(a[mt], b[nt], acc[mt][nt]);
  }

  // epilogue: bias + PE, store tokens, accumulate LN stats (block spans <=2 samples)
  float s0 = 0.f, q0 = 0.f, s1 = 0.f, q1 = 0.f;
  const int b0 = m0 / 196;
#pragma unroll
  for (int mt = 0; mt < 4; mt++) {
#pragma unroll
    for (int nt = 0; nt < 4; nt++) {
      const int col = n0 + n_off + nt * 16 + l16;
      const float bc = bmap[col];
#pragma unroll
      for (int r = 0; r < 4; r++) {
        const int gm = m0 + m_off + mt * 16 + quad * 4 + r;
        const int bb = gm / 196;
        const int ss = gm - bb * 196 + 1;  // class token occupies s=0
        float val = acc[mt][nt][r] + bc + pe[ss * 768 + col];
        out[((size_t)bb * 197 + ss) * 768 + col] = val;
        if (bb == b0) { s0 += val; q0 += val * val; }
        else          { s1 += val; q1 += val * val; }
      }
    }
  }
  for (int off = 32; off > 0; off >>= 1) {
    s0 += __shfl_down(s0, off); q0 += __shfl_down(q0, off);
    s1 += __shfl_down(s1, off); q1 += __shfl_down(q1, off);
  }
  if (lane == 0) {
    atomicAdd(&sums[b0], s0);
    atomicAdd(&sqs[b0], q0);
    if (b0 + 1 < 128) { atomicAdd(&sums[b0 + 1], s1); atomicAdd(&sqs[b0 + 1], q1); }
  }
}

// ---------- class token row (s=0) + its stats ----------
__global__ __launch_bounds__(256) void k_cls(
    const float* __restrict__ ct, const float* __restrict__ pe,
    float* __restrict__ out, float* __restrict__ sums, float* __restrict__ sqs) {
  const int b = blockIdx.x, tid = threadIdx.x;
  float s = 0.f, q = 0.f;
#pragma unroll
  for (int it = 0; it < 3; it++) {
    int j = tid + it * 256;
    float v = ct[j] + pe[j];  // PE row 0
    out[(size_t)b * 197 * 768 + j] = v;
    s += v; q += v * v;
  }
  for (int off = 32; off > 0; off >>= 1) { s += __shfl_down(s, off); q += __shfl_down(q, off); }
  __shared__ float rs[4], rq[4];
  int w = tid >> 6;
  if ((tid & 63) == 0) { rs[w] = s; rq[w] = q; }
  __syncthreads();
  if (tid == 0) {
    atomicAdd(&sums[b], rs[0] + rs[1] + rs[2] + rs[3]);
    atomicAdd(&sqs[b], rq[0] + rq[1] + rq[2] + rq[3]);
  }
}

// ---------- finalize mean/rstd ----------
__global__ void k_fin(const float* __restrict__ sums, const float* __restrict__ sqs,
                      float* __restrict__ mr) {
  int i = threadIdx.x;  // 128
  const float inv = 1.0f / 151296.0f;
  float m = sums[i] * inv;
  float v = sqs[i] * inv - m * m;
  mr[2 * i] = m;
  mr[2 * i + 1] = rsqrtf(v + 1e-5f);
}

// ---------- QKV projection, LN fused into A-frag build ----------
// grid (197 m-tiles of 128 rows over M=25216, 12 heads), 256 thr; wave w: rows w*32..w*32+32
__global__ __launch_bounds__(256) void k_qkv(
    const float* __restrict__ tok, const float* __restrict__ mr,
    const float* __restrict__ lnw, const float* __restrict__ lnb,
    const float* __restrict__ Wq, const float* __restrict__ bq,
    const float* __restrict__ Wk, const float* __restrict__ bk,
    const float* __restrict__ Wv, const float* __restrict__ bv,
    unsigned short* __restrict__ qob, unsigned short* __restrict__ kob,
    unsigned short* __restrict__ vob) {
  const int tid = threadIdx.x;
  const int h = blockIdx.y;
  const int m0 = blockIdx.x * 128;
  const int lane = tid & 63, w = tid >> 6;
  const int quad = lane >> 4, l16 = lane & 15;
  const int m_base = m0 + w * 32;

  const float* Ws[3] = {Wq, Wk, Wv};
  fx4 acc[3][2][4];
#pragma unroll
  for (int a = 0; a < 3; a++)
#pragma unroll
    for (int i = 0; i < 2; i++)
#pragma unroll
      for (int j = 0; j < 4; j++) acc[a][i][j] = (fx4){0.f, 0.f, 0.f, 0.f};

#pragma unroll
  for (int kk = 0; kk < 64; kk += 32) {
    bf16x8 a[2];
#pragma unroll
    for (int mt = 0; mt < 2; mt++) {
      const int m = m_base + mt * 16 + l16;
      const int bb = m / 197;
      const int ss = m - bb * 197;
      const float mean = mr[2 * bb], rstd = mr[2 * bb + 1];
      const int cbase = h * 64 + kk + quad * 8;
      const fx4* px = (const fx4*)(tok + (size_t)m * 768 + cbase);
      const fx4* pw = (const fx4*)(lnw + (size_t)ss * 768 + cbase);
      const fx4* pb = (const fx4*)(lnb + (size_t)ss * 768 + cbase);
      fx4 y0 = (px[0] - mean) * rstd * pw[0] + pb[0];
      fx4 y1 = (px[1] - mean) * rstd * pw[1] + pb[1];
      a[mt] = __builtin_bit_cast(bf16x8, pack8(y0, y1));
    }
#pragma unroll
    for (int mat = 0; mat < 3; mat++) {
#pragma unroll
      for (int nt = 0; nt < 4; nt++) {
        const int n = nt * 16 + l16;
        const fx4* pw = (const fx4*)(Ws[mat] + h * 4096 + n * 64 + kk + quad * 8);
        bf16x8 bf = __builtin_bit_cast(bf16x8, pack8(pw[0], pw[1]));
        acc[mat][0][nt] = MFMA16(a[0], bf, acc[mat][0][nt]);
        acc[mat][1][nt] = MFMA16(a[1], bf, acc[mat][1][nt]);
      }
    }
  }
  const float* Bias[3] = {bq, bk, bv};
  unsigned short* Obuf[3] = {qob, kob, vob};
#pragma unroll
  for (int mt = 0; mt < 2; mt++) {
#pragma unroll
    for (int r = 0; r < 4; r++) {
      const int m = m_base + mt * 16 + quad * 4 + r;
      const int bb = m / 197;
      const int ss = m - bb * 197;
      const size_t rowoff = (((size_t)bb * 12 + h) * 197 + ss) * 64;
#pragma unroll
      for (int mat = 0; mat < 3; mat++) {
#pragma unroll
        for (int nt = 0; nt < 4; nt++) {
          const int e = nt * 16 + l16;
          Obuf[mat][rowoff + e] = f2bf(acc[mat][mt][nt][r] + Bias[mat][h * 64 + e]);
        }
      }
    }
  }
}

// ---------- attention per (b,h); out += P V (residual with tokens already in out) ----------
__global__ __launch_bounds__(256) void k_attn(
    const unsigned short* __restrict__ qb, const unsigned short* __restrict__ kb,
    const unsigned short* __restrict__ vb, float* __restrict__ out) {
  __shared__ __align__(16) unsigned short Vt[64][232];    // V^T, cols padded+zeroed
  __shared__ __align__(16) unsigned short P[4][16][232];  // per-wave P tile (A-layout rows)
  const int tid = threadIdx.x;
  const int bh = blockIdx.x;
  const int b = bh / 12;
  const int h = bh - b * 12;
  const unsigned short* Qp = qb + (size_t)bh * 197 * 64;
  const unsigned short* Kp = kb + (size_t)bh * 197 * 64;
  const unsigned short* Vp = vb + (size_t)bh * 197 * 64;

  for (int idx = tid; idx < 64 * 232; idx += 256) {
    int e = idx / 232;
    int t = idx - e * 232;
    Vt[e][t] = (t < 197) ? Vp[t * 64 + e] : (unsigned short)0;
  }
  for (int idx = tid; idx < 4 * 16 * 24; idx += 256) {  // zero P cols [208,232)
    int wv = idx / 384;
    int rem = idx - wv * 384;
    int r = rem / 24;
    int c = rem - r * 24;
    P[wv][r][208 + c] = 0;
  }
  __syncthreads();

  const int lane = tid & 63;
  const int w = tid >> 6;
  const int quad = lane >> 4;
  const int l16 = lane & 15;

  for (int mt = w; mt < 13; mt += 4) {  // waves run independent m-tiles; no block sync below
    fx4 sacc[13];
#pragma unroll
    for (int nt = 0; nt < 13; nt++) sacc[nt] = (fx4){0.f, 0.f, 0.f, 0.f};
#pragma unroll
    for (int kk = 0; kk < 2; kk++) {
      int qm = mt * 16 + l16;
      qm = (qm < 197) ? qm : 196;  // clamp: results masked at write
      bf16x8 a = *(const bf16x8*)(Qp + qm * 64 + kk * 32 + quad * 8);
#pragma unroll
      for (int nt = 0; nt < 13; nt++) {
        int kn = nt * 16 + l16;
        kn = (kn < 197) ? kn : 196;
        bf16x8 bf = *(const bf16x8*)(Kp + kn * 64 + kk * 32 + quad * 8);
        sacc[nt] = MFMA16(a, bf, sacc[nt]);
      }
    }
    float mx[4] = {-3e38f, -3e38f, -3e38f, -3e38f};
#pragma unroll
    for (int nt = 0; nt < 13; nt++) {
      int col = nt * 16 + l16;
      if (col < 197) {
#pragma unroll
        for (int r = 0; r < 4; r++) mx[r] = fmaxf(mx[r], sacc[nt][r]);
      }
    }
#pragma unroll
    for (int off = 1; off < 16; off <<= 1) {
#pragma unroll
      for (int r = 0; r < 4; r++) mx[r] = fmaxf(mx[r], __shfl_xor(mx[r], off));
    }
    float sm[4] = {0.f, 0.f, 0.f, 0.f};
#pragma unroll
    for (int nt = 0; nt < 13; nt++) {
      int col = nt * 16 + l16;
#pragma unroll
      for (int r = 0; r < 4; r++) {
        float p = (col < 197) ? __expf((sacc[nt][r] - mx[r]) * 0.125f) : 0.f;
        sm[r] += p;
        P[w][quad * 4 + r][col] = f2bf(p);
      }
    }
#pragma unroll
    for (int off = 1; off < 16; off <<= 1) {
#pragma unroll
      for (int r = 0; r < 4; r++) sm[r] += __shfl_xor(sm[r], off);
    }
    __asm__ volatile("s_waitcnt lgkmcnt(0)" ::: "memory");  // P writes -> P reads, same wave
    fx4 oacc[4];
#pragma unroll
    for (int nt = 0; nt < 4; nt++) oacc[nt] = (fx4){0.f, 0.f, 0.f, 0.f};
#pragma unroll
    for (int kk = 0; kk < 7; kk++) {  // K dim padded to 224; pads are zero
      bf16x8 a = *(const bf16x8*)&P[w][l16][kk * 32 + quad * 8];
#pragma unroll
      for (int nt = 0; nt < 4; nt++) {
        bf16x8 bf = *(const bf16x8*)&Vt[nt * 16 + l16][kk * 32 + quad * 8];
        oacc[nt] = MFMA16(a, bf, oacc[nt]);
      }
    }
#pragma unroll
    for (int nt = 0; nt < 4; nt++) {
      const int e = nt * 16 + l16;
#pragma unroll
      for (int r = 0; r < 4; r++) {
        const int ss = mt * 16 + quad * 4 + r;
        if (ss < 197) {
          const size_t oi = ((size_t)b * 197 + ss) * 768 + h * 64 + e;
          out[oi] += oacc[nt][r] / sm[r];  // residual: tokens already stored
        }
      }
    }
  }
}

extern "C" void kernel_launch(void* const* d_in, const int* in_sizes, int n_in,
                              void* d_out, int out_size, void* d_ws, size_t ws_size,
                              hipStream_t stream) {
  (void)in_sizes; (void)n_in; (void)out_size; (void)ws_size;
  const float* img  = (const float*)d_in[0];
  const float* Wmap = (const float*)d_in[1];
  const float* bmap = (const float*)d_in[2];
  const float* ct   = (const float*)d_in[3];
  const float* lnw  = (const float*)d_in[4];
  const float* lnb  = (const float*)d_in[5];
  const float* Wq   = (const float*)d_in[6];
  const float* bq   = (const float*)d_in[7];
  const float* Wk   = (const float*)d_in[8];
  const float* bk   = (const float*)d_in[9];
  const float* Wv   = (const float*)d_in[10];
  const float* bv   = (const float*)d_in[11];
  float* out = (float*)d_out;

  // ws layout (~117.4 MB): pe | sums | sqs | mean_rstd | W_bf16 | q | k | v
  float* pe   = (float*)d_ws;                 // 151296 f
  float* sums = pe + 151296;                  // 128 f
  float* sqs  = sums + 128;                   // 128 f
  float* mr   = sqs + 128;                    // 256 f
  unsigned short* wbf  = (unsigned short*)(mr + 256);      // 589824 u16
  unsigned short* qbuf = wbf + 589824;                     // 19365888 u16 each
  unsigned short* kbuf = qbuf + (size_t)19365888;
  unsigned short* vbuf = kbuf + (size_t)19365888;

  k_pe<<<591, 256, 0, stream>>>(pe, sums, sqs);
  k_cvtw<<<288, 256, 0, stream>>>(Wmap, wbf);
  k_tokens<<<dim3(6, 196), 256, 0, stream>>>(img, wbf, bmap, pe, out, sums, sqs);
  k_cls<<<128, 256, 0, stream>>>(ct, pe, out, sums, sqs);
  k_fin<<<1, 128, 0, stream>>>(sums, sqs, mr);
  k_qkv<<<dim3(197, 12), 256, 0, stream>>>(out, mr, lnw, lnb, Wq, bq, Wk, bk, Wv, bv,
                                           qbuf, kbuf, vbuf);
  k_attn<<<1536, 256, 0, stream>>>(qbuf, kbuf, vbuf, out);
}

// Round 2
// 623.323 us; speedup vs baseline: 1.0349x; 1.0349x over previous
//
#include <hip/hip_runtime.h>

typedef float fx4 __attribute__((ext_vector_type(4)));
typedef __bf16 bf16x8 __attribute__((ext_vector_type(8)));
typedef unsigned short ushort8 __attribute__((ext_vector_type(8)));
typedef unsigned int uint2v __attribute__((ext_vector_type(2)));
typedef unsigned int uint4v __attribute__((ext_vector_type(4)));

#define MFMA16(a, b, c) __builtin_amdgcn_mfma_f32_16x16x32_bf16((a), (b), (c), 0, 0, 0)

__device__ __forceinline__ unsigned short f2bf(float f) {
  unsigned int u = __float_as_uint(f);
  return (unsigned short)((u + 0x7FFFu + ((u >> 16) & 1u)) >> 16);
}

__device__ __forceinline__ ushort8 pack8(fx4 a, fx4 b) {
  ushort8 v;
  v[0] = f2bf(a[0]); v[1] = f2bf(a[1]); v[2] = f2bf(a[2]); v[3] = f2bf(a[3]);
  v[4] = f2bf(b[0]); v[5] = f2bf(b[1]); v[6] = f2bf(b[2]); v[7] = f2bf(b[3]);
  return v;
}

// ---------- PE table + zero stats ----------
__global__ void k_pe(float* __restrict__ pe, float* __restrict__ sums, float* __restrict__ sqs) {
  int idx = blockIdx.x * 256 + threadIdx.x;  // < 197*768 = 151296 exactly
  int s = idx / 768;
  int j = idx - s * 768;
  int jj = j & ~1;
  float ang = (float)s * expf((float)jj * (-9.210340371976184f / 768.0f));
  pe[idx] = (j & 1) ? cosf(ang) : sinf(ang);
  if (blockIdx.x == 0 && threadIdx.x < 128) {
    sums[threadIdx.x] = 0.f;
    sqs[threadIdx.x] = 0.f;
  }
}

// ---------- W_map fp32 -> bf16 ----------
__global__ void k_cvtw(const float* __restrict__ W, unsigned short* __restrict__ wbf) {
  int i = (blockIdx.x * 256 + threadIdx.x) * 8;  // 288 blocks * 256 * 8 = 589824 exactly
  const fx4* p = (const fx4*)(W + i);
  *(ushort8*)(wbf + i) = pack8(p[0], p[1]);
}

// ---------- tokens = patches @ W_map^T + b_map + PE; also LN partial stats ----------
// grid (6 n-tiles, 196 m-tiles), 256 thr. M=25088=196*128, N=768=6*128, K=768.
__global__ __launch_bounds__(256) void k_tokens(
    const float* __restrict__ img, const unsigned short* __restrict__ wbf,
    const float* __restrict__ bmap, const float* __restrict__ pe,
    float* __restrict__ out, float* __restrict__ sums, float* __restrict__ sqs) {
  __shared__ __align__(16) unsigned short As[128][40];  // +8 pad breaks pow2 stride
  __shared__ __align__(16) unsigned short Bs[128][40];
  const int tid = threadIdx.x;
  const int n0 = blockIdx.x * 128;
  const int m0 = blockIdx.y * 128;
  const int lane = tid & 63;
  const int w = tid >> 6;
  const int quad = lane >> 4, l16 = lane & 15;
  const int m_off = (w & 1) * 64, n_off = (w >> 1) * 64;

  fx4 acc[4][4];
#pragma unroll
  for (int i = 0; i < 4; i++)
#pragma unroll
    for (int j = 0; j < 4; j++) acc[i][j] = (fx4){0.f, 0.f, 0.f, 0.f};

  const int srow = tid >> 2;        // 0..63
  const int skc = (tid & 3) * 8;    // 0,8,16,24

  for (int k0 = 0; k0 < 768; k0 += 32) {
    __syncthreads();
#pragma unroll
    for (int rr = 0; rr < 2; rr++) {
      const int r = srow + rr * 64;
      const fx4* pa = (const fx4*)(img + (size_t)(m0 + r) * 768 + k0 + skc);
      *(ushort8*)&As[r][skc] = pack8(pa[0], pa[1]);
      *(ushort8*)&Bs[r][skc] = *(const ushort8*)(wbf + (size_t)(n0 + r) * 768 + k0 + skc);
    }
    __syncthreads();
    bf16x8 a[4], b[4];
#pragma unroll
    for (int mt = 0; mt < 4; mt++) a[mt] = *(const bf16x8*)&As[m_off + mt * 16 + l16][quad * 8];
#pragma unroll
    for (int nt = 0; nt < 4; nt++) b[nt] = *(const bf16x8*)&Bs[n_off + nt * 16 + l16][quad * 8];
#pragma unroll
    for (int mt = 0; mt < 4; mt++)
#pragma unroll
      for (int nt = 0; nt < 4; nt++) acc[mt][nt] = MFMA16(a[mt], b[nt], acc[mt][nt]);
  }

  // epilogue: bias + PE, store tokens, accumulate LN stats (block spans <=2 samples)
  float s0 = 0.f, q0 = 0.f, s1 = 0.f, q1 = 0.f;
  const int b0 = m0 / 196;
#pragma unroll
  for (int mt = 0; mt < 4; mt++) {
#pragma unroll
    for (int nt = 0; nt < 4; nt++) {
      const int col = n0 + n_off + nt * 16 + l16;
      const float bc = bmap[col];
#pragma unroll
      for (int r = 0; r < 4; r++) {
        const int gm = m0 + m_off + mt * 16 + quad * 4 + r;
        const int bb = gm / 196;
        const int ss = gm - bb * 196 + 1;  // class token occupies s=0
        float val = acc[mt][nt][r] + bc + pe[ss * 768 + col];
        out[((size_t)bb * 197 + ss) * 768 + col] = val;
        if (bb == b0) { s0 += val; q0 += val * val; }
        else          { s1 += val; q1 += val * val; }
      }
    }
  }
  for (int off = 32; off > 0; off >>= 1) {
    s0 += __shfl_down(s0, off); q0 += __shfl_down(q0, off);
    s1 += __shfl_down(s1, off); q1 += __shfl_down(q1, off);
  }
  if (lane == 0) {
    atomicAdd(&sums[b0], s0);
    atomicAdd(&sqs[b0], q0);
    if (b0 + 1 < 128) { atomicAdd(&sums[b0 + 1], s1); atomicAdd(&sqs[b0 + 1], q1); }
  }
}

// ---------- class token row (s=0) + its stats ----------
__global__ __launch_bounds__(256) void k_cls(
    const float* __restrict__ ct, const float* __restrict__ pe,
    float* __restrict__ out, float* __restrict__ sums, float* __restrict__ sqs) {
  const int b = blockIdx.x, tid = threadIdx.x;
  float s = 0.f, q = 0.f;
#pragma unroll
  for (int it = 0; it < 3; it++) {
    int j = tid + it * 256;
    float v = ct[j] + pe[j];  // PE row 0
    out[(size_t)b * 197 * 768 + j] = v;
    s += v; q += v * v;
  }
  for (int off = 32; off > 0; off >>= 1) { s += __shfl_down(s, off); q += __shfl_down(q, off); }
  __shared__ float rs[4], rq[4];
  int w = tid >> 6;
  if ((tid & 63) == 0) { rs[w] = s; rq[w] = q; }
  __syncthreads();
  if (tid == 0) {
    atomicAdd(&sums[b], rs[0] + rs[1] + rs[2] + rs[3]);
    atomicAdd(&sqs[b], rq[0] + rq[1] + rq[2] + rq[3]);
  }
}

// ---------- finalize mean/rstd ----------
__global__ void k_fin(const float* __restrict__ sums, const float* __restrict__ sqs,
                      float* __restrict__ mr) {
  int i = threadIdx.x;  // 128
  const float inv = 1.0f / 151296.0f;
  float m = sums[i] * inv;
  float v = sqs[i] * inv - m * m;
  mr[2 * i] = m;
  mr[2 * i + 1] = rsqrtf(v + 1e-5f);
}

// ---------- QKV projection, LN fused into A/B-frag build ----------
// grid (197 m-tiles of 128 rows over M=25216, 12 heads), 256 thr; wave w: rows w*32..+32
// Q,K written [bh][s][e]; V written TRANSPOSED [bh][e][s] (stride 200) via swapped-operand
// MFMA (A=Wv, B=X_ln) whose C-layout (col=s) gives 32B-coalesced transposed stores.
__global__ __launch_bounds__(256) void k_qkv(
    const float* __restrict__ tok, const float* __restrict__ mr,
    const float* __restrict__ lnw, const float* __restrict__ lnb,
    const float* __restrict__ Wq, const float* __restrict__ bq,
    const float* __restrict__ Wk, const float* __restrict__ bk,
    const float* __restrict__ Wv, const float* __restrict__ bv,
    unsigned short* __restrict__ qob, unsigned short* __restrict__ kob,
    unsigned short* __restrict__ vtob) {
  const int tid = threadIdx.x;
  const int h = blockIdx.y;
  const int m0 = blockIdx.x * 128;
  const int lane = tid & 63, w = tid >> 6;
  const int quad = lane >> 4, l16 = lane & 15;
  const int m_base = m0 + w * 32;

  fx4 accq[2][4], acck[2][4], accv[4][2];
#pragma unroll
  for (int i = 0; i < 2; i++)
#pragma unroll
    for (int j = 0; j < 4; j++) {
      accq[i][j] = (fx4){0.f, 0.f, 0.f, 0.f};
      acck[i][j] = (fx4){0.f, 0.f, 0.f, 0.f};
      accv[j][i] = (fx4){0.f, 0.f, 0.f, 0.f};
    }

#pragma unroll
  for (int kk = 0; kk < 64; kk += 32) {
    bf16x8 a[2];  // LN'd X fragments: lane l16 = row, k = kk + quad*8 + j
#pragma unroll
    for (int mt = 0; mt < 2; mt++) {
      const int m = m_base + mt * 16 + l16;
      const int bb = m / 197;
      const int ss = m - bb * 197;
      const float mean = mr[2 * bb], rstd = mr[2 * bb + 1];
      const int cbase = h * 64 + kk + quad * 8;
      const fx4* px = (const fx4*)(tok + (size_t)m * 768 + cbase);
      const fx4* pw = (const fx4*)(lnw + (size_t)ss * 768 + cbase);
      const fx4* pb = (const fx4*)(lnb + (size_t)ss * 768 + cbase);
      fx4 y0 = (px[0] - mean) * rstd * pw[0] + pb[0];
      fx4 y1 = (px[1] - mean) * rstd * pw[1] + pb[1];
      a[mt] = __builtin_bit_cast(bf16x8, pack8(y0, y1));
    }
    // Q, K: D[m][e] = A(X) * B(W)
#pragma unroll
    for (int nt = 0; nt < 4; nt++) {
      const int n = nt * 16 + l16;
      const fx4* pq = (const fx4*)(Wq + h * 4096 + n * 64 + kk + quad * 8);
      bf16x8 bfq = __builtin_bit_cast(bf16x8, pack8(pq[0], pq[1]));
      accq[0][nt] = MFMA16(a[0], bfq, accq[0][nt]);
      accq[1][nt] = MFMA16(a[1], bfq, accq[1][nt]);
      const fx4* pk = (const fx4*)(Wk + h * 4096 + n * 64 + kk + quad * 8);
      bf16x8 bfk = __builtin_bit_cast(bf16x8, pack8(pk[0], pk[1]));
      acck[0][nt] = MFMA16(a[0], bfk, acck[0][nt]);
      acck[1][nt] = MFMA16(a[1], bfk, acck[1][nt]);
    }
    // V^T: D[e][s] = A(Wv) * B(X)
#pragma unroll
    for (int et = 0; et < 4; et++) {
      const int e = et * 16 + l16;
      const fx4* pv = (const fx4*)(Wv + h * 4096 + e * 64 + kk + quad * 8);
      bf16x8 av = __builtin_bit_cast(bf16x8, pack8(pv[0], pv[1]));
      accv[et][0] = MFMA16(av, a[0], accv[et][0]);
      accv[et][1] = MFMA16(av, a[1], accv[et][1]);
    }
  }
  // Q/K epilogue: C-layout col=e=l16, row=m=quad*4+r
#pragma unroll
  for (int mt = 0; mt < 2; mt++) {
#pragma unroll
    for (int r = 0; r < 4; r++) {
      const int m = m_base + mt * 16 + quad * 4 + r;
      const int bb = m / 197;
      const int ss = m - bb * 197;
      const size_t rowoff = (((size_t)bb * 12 + h) * 197 + ss) * 64;
#pragma unroll
      for (int nt = 0; nt < 4; nt++) {
        const int e = nt * 16 + l16;
        qob[rowoff + e] = f2bf(accq[mt][nt][r] + bq[h * 64 + e]);
        kob[rowoff + e] = f2bf(acck[mt][nt][r] + bk[h * 64 + e]);
      }
    }
  }
  // V^T epilogue: C-layout col=s=l16, row=e=quad*4+r; 16 consecutive lanes -> 32B runs
#pragma unroll
  for (int et = 0; et < 4; et++) {
#pragma unroll
    for (int r = 0; r < 4; r++) {
      const int e = et * 16 + quad * 4 + r;
      const float bvv = bv[h * 64 + e];
#pragma unroll
      for (int mt = 0; mt < 2; mt++) {
        const int m = m_base + mt * 16 + l16;
        const int bb = m / 197;
        const int ss = m - bb * 197;
        vtob[((size_t)(bb * 12 + h) * 64 + e) * 200 + ss] = f2bf(accv[et][mt][r] + bvv);
      }
    }
  }
}

// ---------- attention per (b,h), S^T formulation; out += P V (residual) ----------
// S^T = K Q^T: C-layout col = query m = l16 -> softmax reduce = 2 shfl rounds;
// P written t-contiguous (13 ds_write_b64), PV A-frags read from global vt.
// LDS = per-wave P slab only (29696 B) -> 4 blocks/CU with launch_bounds(256,4).
__global__ __launch_bounds__(256, 4) void k_attn(
    const unsigned short* __restrict__ qb, const unsigned short* __restrict__ kb,
    const unsigned short* __restrict__ vtb, float* __restrict__ out) {
  __shared__ __align__(16) unsigned short Pt[4][16][232];  // per-wave [m_local][t], stride 232
  const int tid = threadIdx.x;
  const int bh = blockIdx.x;
  const int b = bh / 12;
  const int h = bh - b * 12;
  const unsigned short* Qp = qb + (size_t)bh * 197 * 64;
  const unsigned short* Kp = kb + (size_t)bh * 197 * 64;
  const unsigned short* Vtp = vtb + (size_t)bh * 64 * 200;
  const int lane = tid & 63;
  const int w = tid >> 6;
  const int quad = lane >> 4;
  const int l16 = lane & 15;

  // zero pad cols [208,224) once (read by PV kk=6 quads 2,3); cols [192,208) are
  // written with masked zeros every m-tile by the nt=12 pass.
  if (quad < 2) *(uint4v*)&Pt[w][l16][208 + quad * 8] = (uint4v){0u, 0u, 0u, 0u};

  for (int mt = w; mt < 13; mt += 4) {  // waves independent; no block barrier anywhere
    int qm = mt * 16 + l16;
    qm = (qm < 197) ? qm : 196;  // clamp; masked at output
    fx4 sacc[13];
#pragma unroll
    for (int nt = 0; nt < 13; nt++) sacc[nt] = (fx4){0.f, 0.f, 0.f, 0.f};
#pragma unroll
    for (int kk = 0; kk < 2; kk++) {
      bf16x8 qf = *(const bf16x8*)(Qp + qm * 64 + kk * 32 + quad * 8);
#pragma unroll
      for (int nt = 0; nt < 13; nt++) {
        int tn = nt * 16 + l16;
        tn = (tn < 197) ? tn : 196;
        bf16x8 kf = *(const bf16x8*)(Kp + tn * 64 + kk * 32 + quad * 8);
        sacc[nt] = MFMA16(kf, qf, sacc[nt]);  // D[t][m]: col=m=l16, row=t=quad*4+r
      }
    }
    // softmax over t (no max-sub: |s|*0.125 < ~0.5 by construction, exp safe)
    float sm = 0.f;
#pragma unroll
    for (int nt = 0; nt < 13; nt++) {
      float p[4];
#pragma unroll
      for (int r = 0; r < 4; r++) {
        const bool valid = (nt < 12) | (quad * 4 + r < 5);  // t = nt*16+quad*4+r < 197
        p[r] = valid ? __expf(sacc[nt][r] * 0.125f) : 0.f;
        sm += p[r];
      }
      uint2v pk;
      pk[0] = (unsigned int)f2bf(p[0]) | ((unsigned int)f2bf(p[1]) << 16);
      pk[1] = (unsigned int)f2bf(p[2]) | ((unsigned int)f2bf(p[3]) << 16);
      *(uint2v*)&Pt[w][l16][nt * 16 + quad * 4] = pk;
    }
    sm += __shfl_xor(sm, 16);
    sm += __shfl_xor(sm, 32);
    const float inv = 1.0f / sm;
    __asm__ volatile("s_waitcnt lgkmcnt(0)" ::: "memory");  // P writes -> P reads, same wave
    fx4 oacc[4];
#pragma unroll
    for (int et = 0; et < 4; et++) oacc[et] = (fx4){0.f, 0.f, 0.f, 0.f};
#pragma unroll
    for (int kk = 0; kk < 7; kk++) {
      bf16x8 pf = *(const bf16x8*)&Pt[w][l16][kk * 32 + quad * 8];
#pragma unroll
      for (int et = 0; et < 4; et++) {
        // A-frag of V^T from global: row e = et*16+l16, k = t (stride 200; overreads
        // past t=197 hit zero-P slots so contribute 0)
        bf16x8 vf = *(const bf16x8*)(Vtp + (et * 16 + l16) * 200 + kk * 32 + quad * 8);
        oacc[et] = MFMA16(vf, pf, oacc[et]);  // D[e][m]: col=m=l16, row=e
      }
    }
    const int sg = mt * 16 + l16;
    if (sg < 197) {
      float* op = out + ((size_t)b * 197 + sg) * 768 + h * 64 + quad * 4;
#pragma unroll
      for (int et = 0; et < 4; et++) {
        fx4 cur = *(const fx4*)(op + et * 16);
        cur += oacc[et] * inv;
        *(fx4*)(op + et * 16) = cur;
      }
    }
  }
}

extern "C" void kernel_launch(void* const* d_in, const int* in_sizes, int n_in,
                              void* d_out, int out_size, void* d_ws, size_t ws_size,
                              hipStream_t stream) {
  (void)in_sizes; (void)n_in; (void)out_size; (void)ws_size;
  const float* img  = (const float*)d_in[0];
  const float* Wmap = (const float*)d_in[1];
  const float* bmap = (const float*)d_in[2];
  const float* ct   = (const float*)d_in[3];
  const float* lnw  = (const float*)d_in[4];
  const float* lnb  = (const float*)d_in[5];
  const float* Wq   = (const float*)d_in[6];
  const float* bq   = (const float*)d_in[7];
  const float* Wk   = (const float*)d_in[8];
  const float* bk   = (const float*)d_in[9];
  const float* Wv   = (const float*)d_in[10];
  const float* bv   = (const float*)d_in[11];
  float* out = (float*)d_out;

  // ws layout (~114.8 MB): pe | sums | sqs | mean_rstd | W_bf16 | q | k | vt
  float* pe   = (float*)d_ws;                 // 151296 f
  float* sums = pe + 151296;                  // 128 f
  float* sqs  = sums + 128;                   // 128 f
  float* mr   = sqs + 128;                    // 256 f
  unsigned short* wbf   = (unsigned short*)(mr + 256);     // 589824 u16
  unsigned short* qbuf  = wbf + 589824;                    // 19365888 u16
  unsigned short* kbuf  = qbuf + (size_t)19365888;         // 19365888 u16
  unsigned short* vtbuf = kbuf + (size_t)19365888;         // 1536*64*200 + 32 slack u16

  k_pe<<<591, 256, 0, stream>>>(pe, sums, sqs);
  k_cvtw<<<288, 256, 0, stream>>>(Wmap, wbf);
  k_tokens<<<dim3(6, 196), 256, 0, stream>>>(img, wbf, bmap, pe, out, sums, sqs);
  k_cls<<<128, 256, 0, stream>>>(ct, pe, out, sums, sqs);
  k_fin<<<1, 128, 0, stream>>>(sums, sqs, mr);
  k_qkv<<<dim3(197, 12), 256, 0, stream>>>(out, mr, lnw, lnb, Wq, bq, Wk, bk, Wv, bv,
                                           qbuf, kbuf, vtbuf);
  k_attn<<<1536, 256, 0, stream>>>(qbuf, kbuf, vtbuf, out);
}

// Round 3
// 515.395 us; speedup vs baseline: 1.2516x; 1.2094x over previous
//
#include <hip/hip_runtime.h>

typedef float fx4 __attribute__((ext_vector_type(4)));
typedef __bf16 bf16x8 __attribute__((ext_vector_type(8)));
typedef unsigned short ushort8 __attribute__((ext_vector_type(8)));
typedef unsigned int uint2v __attribute__((ext_vector_type(2)));
typedef unsigned int uint4v __attribute__((ext_vector_type(4)));

#define MFMA16(a, b, c) __builtin_amdgcn_mfma_f32_16x16x32_bf16((a), (b), (c), 0, 0, 0)

__device__ __forceinline__ unsigned short f2bf(float f) {
  unsigned int u = __float_as_uint(f);
  return (unsigned short)((u + 0x7FFFu + ((u >> 16) & 1u)) >> 16);
}

__device__ __forceinline__ ushort8 pack8(fx4 a, fx4 b) {
  ushort8 v;
  v[0] = f2bf(a[0]); v[1] = f2bf(a[1]); v[2] = f2bf(a[2]); v[3] = f2bf(a[3]);
  v[4] = f2bf(b[0]); v[5] = f2bf(b[1]); v[6] = f2bf(b[2]); v[7] = f2bf(b[3]);
  return v;
}

// ---------- PE table + zero stats ----------
__global__ void k_pe(float* __restrict__ pe, float* __restrict__ sums, float* __restrict__ sqs) {
  int idx = blockIdx.x * 256 + threadIdx.x;  // < 197*768 = 151296 exactly
  int s = idx / 768;
  int j = idx - s * 768;
  int jj = j & ~1;
  float ang = (float)s * expf((float)jj * (-9.210340371976184f / 768.0f));
  pe[idx] = (j & 1) ? cosf(ang) : sinf(ang);
  if (blockIdx.x == 0 && threadIdx.x < 128) {
    sums[threadIdx.x] = 0.f;
    sqs[threadIdx.x] = 0.f;
  }
}

// ---------- W_map fp32 -> bf16 ----------
__global__ void k_cvtw(const float* __restrict__ W, unsigned short* __restrict__ wbf) {
  int i = (blockIdx.x * 256 + threadIdx.x) * 8;  // 288 blocks * 256 * 8 = 589824 exactly
  const fx4* p = (const fx4*)(W + i);
  *(ushort8*)(wbf + i) = pack8(p[0], p[1]);
}

// ---------- tokens = patches @ W_map^T + b_map + PE; also LN partial stats ----------
// grid (6 n-tiles, 196 m-tiles), 256 thr. M=25088=196*128, N=768=6*128, K=768.
__global__ __launch_bounds__(256) void k_tokens(
    const float* __restrict__ img, const unsigned short* __restrict__ wbf,
    const float* __restrict__ bmap, const float* __restrict__ pe,
    float* __restrict__ out, float* __restrict__ sums, float* __restrict__ sqs) {
  __shared__ __align__(16) unsigned short As[128][40];  // +8 pad breaks pow2 stride
  __shared__ __align__(16) unsigned short Bs[128][40];
  const int tid = threadIdx.x;
  const int n0 = blockIdx.x * 128;
  const int m0 = blockIdx.y * 128;
  const int lane = tid & 63;
  const int w = tid >> 6;
  const int quad = lane >> 4, l16 = lane & 15;
  const int m_off = (w & 1) * 64, n_off = (w >> 1) * 64;

  fx4 acc[4][4];
#pragma unroll
  for (int i = 0; i < 4; i++)
#pragma unroll
    for (int j = 0; j < 4; j++) acc[i][j] = (fx4){0.f, 0.f, 0.f, 0.f};

  const int srow = tid >> 2;        // 0..63
  const int skc = (tid & 3) * 8;    // 0,8,16,24

  for (int k0 = 0; k0 < 768; k0 += 32) {
    __syncthreads();
#pragma unroll
    for (int rr = 0; rr < 2; rr++) {
      const int r = srow + rr * 64;
      const fx4* pa = (const fx4*)(img + (size_t)(m0 + r) * 768 + k0 + skc);
      *(ushort8*)&As[r][skc] = pack8(pa[0], pa[1]);
      *(ushort8*)&Bs[r][skc] = *(const ushort8*)(wbf + (size_t)(n0 + r) * 768 + k0 + skc);
    }
    __syncthreads();
    bf16x8 a[4], b[4];
#pragma unroll
    for (int mt = 0; mt < 4; mt++) a[mt] = *(const bf16x8*)&As[m_off + mt * 16 + l16][quad * 8];
#pragma unroll
    for (int nt = 0; nt < 4; nt++) b[nt] = *(const bf16x8*)&Bs[n_off + nt * 16 + l16][quad * 8];
#pragma unroll
    for (int mt = 0; mt < 4; mt++)
#pragma unroll
      for (int nt = 0; nt < 4; nt++) acc[mt][nt] = MFMA16(a[mt], b[nt], acc[mt][nt]);
  }

  // epilogue: bias + PE, store tokens, accumulate LN stats (block spans <=2 samples)
  float s0 = 0.f, q0 = 0.f, s1 = 0.f, q1 = 0.f;
  const int b0 = m0 / 196;
#pragma unroll
  for (int mt = 0; mt < 4; mt++) {
#pragma unroll
    for (int nt = 0; nt < 4; nt++) {
      const int col = n0 + n_off + nt * 16 + l16;
      const float bc = bmap[col];
#pragma unroll
      for (int r = 0; r < 4; r++) {
        const int gm = m0 + m_off + mt * 16 + quad * 4 + r;
        const int bb = gm / 196;
        const int ss = gm - bb * 196 + 1;  // class token occupies s=0
        float val = acc[mt][nt][r] + bc + pe[ss * 768 + col];
        out[((size_t)bb * 197 + ss) * 768 + col] = val;
        if (bb == b0) { s0 += val; q0 += val * val; }
        else          { s1 += val; q1 += val * val; }
      }
    }
  }
  for (int off = 32; off > 0; off >>= 1) {
    s0 += __shfl_down(s0, off); q0 += __shfl_down(q0, off);
    s1 += __shfl_down(s1, off); q1 += __shfl_down(q1, off);
  }
  if (lane == 0) {
    atomicAdd(&sums[b0], s0);
    atomicAdd(&sqs[b0], q0);
    if (b0 + 1 < 128) { atomicAdd(&sums[b0 + 1], s1); atomicAdd(&sqs[b0 + 1], q1); }
  }
}

// ---------- class token row (s=0) + its stats ----------
__global__ __launch_bounds__(256) void k_cls(
    const float* __restrict__ ct, const float* __restrict__ pe,
    float* __restrict__ out, float* __restrict__ sums, float* __restrict__ sqs) {
  const int b = blockIdx.x, tid = threadIdx.x;
  float s = 0.f, q = 0.f;
#pragma unroll
  for (int it = 0; it < 3; it++) {
    int j = tid + it * 256;
    float v = ct[j] + pe[j];  // PE row 0
    out[(size_t)b * 197 * 768 + j] = v;
    s += v; q += v * v;
  }
  for (int off = 32; off > 0; off >>= 1) { s += __shfl_down(s, off); q += __shfl_down(q, off); }
  __shared__ float rs[4], rq[4];
  int w = tid >> 6;
  if ((tid & 63) == 0) { rs[w] = s; rq[w] = q; }
  __syncthreads();
  if (tid == 0) {
    atomicAdd(&sums[b], rs[0] + rs[1] + rs[2] + rs[3]);
    atomicAdd(&sqs[b], rq[0] + rq[1] + rq[2] + rq[3]);
  }
}

// ---------- finalize mean/rstd ----------
__global__ void k_fin(const float* __restrict__ sums, const float* __restrict__ sqs,
                      float* __restrict__ mr) {
  int i = threadIdx.x;  // 128
  const float inv = 1.0f / 151296.0f;
  float m = sums[i] * inv;
  float v = sqs[i] * inv - m * m;
  mr[2 * i] = m;
  mr[2 * i + 1] = rsqrtf(v + 1e-5f);
}

// ---------- QKV projection, LN fused into A/B-frag build ----------
// grid (197 m-tiles of 128 rows over M=25216, 12 heads), 256 thr; wave w: rows w*32..+32
// Q,K written [bh][s][e]; V written TRANSPOSED [bh][e][s] (stride 200) via swapped-operand
// MFMA (A=Wv, B=X_ln) whose C-layout (col=s) gives 32B-coalesced transposed stores.
__global__ __launch_bounds__(256) void k_qkv(
    const float* __restrict__ tok, const float* __restrict__ mr,
    const float* __restrict__ lnw, const float* __restrict__ lnb,
    const float* __restrict__ Wq, const float* __restrict__ bq,
    const float* __restrict__ Wk, const float* __restrict__ bk,
    const float* __restrict__ Wv, const float* __restrict__ bv,
    unsigned short* __restrict__ qob, unsigned short* __restrict__ kob,
    unsigned short* __restrict__ vtob) {
  const int tid = threadIdx.x;
  const int h = blockIdx.y;
  const int m0 = blockIdx.x * 128;
  const int lane = tid & 63, w = tid >> 6;
  const int quad = lane >> 4, l16 = lane & 15;
  const int m_base = m0 + w * 32;

  fx4 accq[2][4], acck[2][4], accv[4][2];
#pragma unroll
  for (int i = 0; i < 2; i++)
#pragma unroll
    for (int j = 0; j < 4; j++) {
      accq[i][j] = (fx4){0.f, 0.f, 0.f, 0.f};
      acck[i][j] = (fx4){0.f, 0.f, 0.f, 0.f};
      accv[j][i] = (fx4){0.f, 0.f, 0.f, 0.f};
    }

#pragma unroll
  for (int kk = 0; kk < 64; kk += 32) {
    bf16x8 a[2];  // LN'd X fragments: lane l16 = row, k = kk + quad*8 + j
#pragma unroll
    for (int mt = 0; mt < 2; mt++) {
      const int m = m_base + mt * 16 + l16;
      const int bb = m / 197;
      const int ss = m - bb * 197;
      const float mean = mr[2 * bb], rstd = mr[2 * bb + 1];
      const int cbase = h * 64 + kk + quad * 8;
      const fx4* px = (const fx4*)(tok + (size_t)m * 768 + cbase);
      const fx4* pw = (const fx4*)(lnw + (size_t)ss * 768 + cbase);
      const fx4* pb = (const fx4*)(lnb + (size_t)ss * 768 + cbase);
      fx4 y0 = (px[0] - mean) * rstd * pw[0] + pb[0];
      fx4 y1 = (px[1] - mean) * rstd * pw[1] + pb[1];
      a[mt] = __builtin_bit_cast(bf16x8, pack8(y0, y1));
    }
    // Q, K: D[m][e] = A(X) * B(W)
#pragma unroll
    for (int nt = 0; nt < 4; nt++) {
      const int n = nt * 16 + l16;
      const fx4* pq = (const fx4*)(Wq + h * 4096 + n * 64 + kk + quad * 8);
      bf16x8 bfq = __builtin_bit_cast(bf16x8, pack8(pq[0], pq[1]));
      accq[0][nt] = MFMA16(a[0], bfq, accq[0][nt]);
      accq[1][nt] = MFMA16(a[1], bfq, accq[1][nt]);
      const fx4* pk = (const fx4*)(Wk + h * 4096 + n * 64 + kk + quad * 8);
      bf16x8 bfk = __builtin_bit_cast(bf16x8, pack8(pk[0], pk[1]));
      acck[0][nt] = MFMA16(a[0], bfk, acck[0][nt]);
      acck[1][nt] = MFMA16(a[1], bfk, acck[1][nt]);
    }
    // V^T: D[e][s] = A(Wv) * B(X)
#pragma unroll
    for (int et = 0; et < 4; et++) {
      const int e = et * 16 + l16;
      const fx4* pv = (const fx4*)(Wv + h * 4096 + e * 64 + kk + quad * 8);
      bf16x8 av = __builtin_bit_cast(bf16x8, pack8(pv[0], pv[1]));
      accv[et][0] = MFMA16(av, a[0], accv[et][0]);
      accv[et][1] = MFMA16(av, a[1], accv[et][1]);
    }
  }
  // Q/K epilogue: C-layout col=e=l16, row=m=quad*4+r
#pragma unroll
  for (int mt = 0; mt < 2; mt++) {
#pragma unroll
    for (int r = 0; r < 4; r++) {
      const int m = m_base + mt * 16 + quad * 4 + r;
      const int bb = m / 197;
      const int ss = m - bb * 197;
      const size_t rowoff = (((size_t)bb * 12 + h) * 197 + ss) * 64;
#pragma unroll
      for (int nt = 0; nt < 4; nt++) {
        const int e = nt * 16 + l16;
        qob[rowoff + e] = f2bf(accq[mt][nt][r] + bq[h * 64 + e]);
        kob[rowoff + e] = f2bf(acck[mt][nt][r] + bk[h * 64 + e]);
      }
    }
  }
  // V^T epilogue: C-layout col=s=l16, row=e=quad*4+r; 16 consecutive lanes -> 32B runs
#pragma unroll
  for (int et = 0; et < 4; et++) {
#pragma unroll
    for (int r = 0; r < 4; r++) {
      const int e = et * 16 + quad * 4 + r;
      const float bvv = bv[h * 64 + e];
#pragma unroll
      for (int mt = 0; mt < 2; mt++) {
        const int m = m_base + mt * 16 + l16;
        const int bb = m / 197;
        const int ss = m - bb * 197;
        vtob[((size_t)(bb * 12 + h) * 64 + e) * 200 + ss] = f2bf(accv[et][mt][r] + bvv);
      }
    }
  }
}

// ---------- attention per (b,h), S^T formulation ----------
// K and V^T staged ONCE per block into fragment-linear LDS (base + lane*16B blobs,
// conflict-free ds_read_b128). P never touches LDS: the C-layout -> B-frag transform
// is an intra-column quad permute done with __shfl. No barriers after staging.
__global__ __launch_bounds__(256) void k_attn(
    const unsigned short* __restrict__ qb, const unsigned short* __restrict__ kb,
    const unsigned short* __restrict__ vtb, float* __restrict__ out) {
  __shared__ __align__(16) ushort8 Kf[26 * 64];   // [nt][kk][lane] 26624 B
  __shared__ __align__(16) ushort8 Vf[28 * 64];   // [et][kk7][lane] 28672 B
  const int tid = threadIdx.x;
  const int bh = blockIdx.x;
  const int b = bh / 12;
  const int h = bh - b * 12;
  const unsigned short* Qp = qb + (size_t)bh * 197 * 64;
  const unsigned short* Kp = kb + (size_t)bh * 197 * 64;
  const unsigned short* Vtp = vtb + (size_t)bh * 64 * 200;
  const int lane = tid & 63;
  const int w = tid >> 6;
  const int quad = lane >> 4;
  const int l16 = lane & 15;

  // stage K: blob i -> (nt = i>>7, kk = (i>>6)&1, lane = i&63); row t clamped
  for (int i = tid; i < 26 * 64; i += 256) {
    const int ln = i & 63, g = i >> 6;
    const int kk = g & 1, nt = g >> 1;
    int t = nt * 16 + (ln & 15);
    t = (t < 197) ? t : 196;
    const int d0 = kk * 32 + (ln >> 4) * 8;
    Kf[i] = *(const ushort8*)(Kp + t * 64 + d0);
  }
  // stage V^T: blob i -> (et = g/7, kk = g%7, lane); t-chunks >=200 clamped (masked by P=0)
  for (int i = tid; i < 28 * 64; i += 256) {
    const int ln = i & 63, g = i >> 6;
    const int kk = g % 7, et = g / 7;
    const int e = et * 16 + (ln & 15);
    int t0 = kk * 32 + (ln >> 4) * 8;
    t0 = (t0 <= 192) ? t0 : 0;  // garbage rows multiplied by zero P entries
    Vf[i] = *(const ushort8*)(Vtp + e * 200 + t0);
  }
  __syncthreads();

  const int src0 = l16 + ((quad & 1) << 5);  // lane of quad (2q)&3, same column
  const int src1 = src0 + 16;                // lane of quad (2q+1)&3

  for (int mt = w; mt < 13; mt += 4) {  // waves independent; no barrier in loop
    int qm = mt * 16 + l16;
    qm = (qm < 197) ? qm : 196;  // clamp; masked at output
    fx4 sacc[13];
#pragma unroll
    for (int nt = 0; nt < 13; nt++) sacc[nt] = (fx4){0.f, 0.f, 0.f, 0.f};
#pragma unroll
    for (int kk = 0; kk < 2; kk++) {
      bf16x8 qf = *(const bf16x8*)(Qp + qm * 64 + kk * 32 + quad * 8);
#pragma unroll
      for (int nt = 0; nt < 13; nt++) {
        bf16x8 kf = __builtin_bit_cast(bf16x8, Kf[(nt * 2 + kk) * 64 + lane]);
        sacc[nt] = MFMA16(kf, qf, sacc[nt]);  // D[t][m]: col=m=l16, row=t=quad*4+r
      }
    }
    // softmax over t (no max-sub: |s|*0.125 small by construction)
    float sm = 0.f;
    uint2v pk[13];
#pragma unroll
    for (int nt = 0; nt < 13; nt++) {
      float p[4];
#pragma unroll
      for (int r = 0; r < 4; r++) {
        const bool valid = (nt < 12) | (quad * 4 + r < 5);  // t = nt*16+quad*4+r < 197
        p[r] = valid ? __expf(sacc[nt][r] * 0.125f) : 0.f;
        sm += p[r];
      }
      pk[nt][0] = (unsigned int)f2bf(p[0]) | ((unsigned int)f2bf(p[1]) << 16);
      pk[nt][1] = (unsigned int)f2bf(p[2]) | ((unsigned int)f2bf(p[3]) << 16);
    }
    sm += __shfl_xor(sm, 16);
    sm += __shfl_xor(sm, 32);
    const float inv = 1.0f / sm;

    fx4 oacc[4];
#pragma unroll
    for (int et = 0; et < 4; et++) oacc[et] = (fx4){0.f, 0.f, 0.f, 0.f};
#pragma unroll
    for (int kk = 0; kk < 7; kk++) {
      // assemble P B-frag: halves j=0..3 from quad (2q)&3, j=4..7 from (2q+1)&3,
      // register nt' = 2kk + (q>>1); kk=6 upper half (t>=208) is zero.
      uint4v pf;
      if (kk < 6) {
        const int nA = 2 * kk, nB = 2 * kk + 1;
#pragma unroll
        for (int d = 0; d < 2; d++) {
          int a0 = __shfl((int)pk[nA][d], src0, 64);
          int b0 = __shfl((int)pk[nB][d], src0, 64);
          pf[d] = (unsigned int)((quad < 2) ? a0 : b0);
          int a1 = __shfl((int)pk[nA][d], src1, 64);
          int b1 = __shfl((int)pk[nB][d], src1, 64);
          pf[2 + d] = (unsigned int)((quad < 2) ? a1 : b1);
        }
      } else {
#pragma unroll
        for (int d = 0; d < 2; d++) {
          int a0 = __shfl((int)pk[12][d], src0, 64);
          pf[d] = (quad < 2) ? (unsigned int)a0 : 0u;
          int a1 = __shfl((int)pk[12][d], src1, 64);
          pf[2 + d] = (quad < 2) ? (unsigned int)a1 : 0u;
        }
      }
      bf16x8 pfrag = __builtin_bit_cast(bf16x8, pf);
#pragma unroll
      for (int et = 0; et < 4; et++) {
        bf16x8 vf = __builtin_bit_cast(bf16x8, Vf[(et * 7 + kk) * 64 + lane]);
        oacc[et] = MFMA16(vf, pfrag, oacc[et]);  // D[e][m]: col=m=l16, row=e
      }
    }
    const int sg = mt * 16 + l16;
    if (sg < 197) {
      float* op = out + ((size_t)b * 197 + sg) * 768 + h * 64 + quad * 4;
#pragma unroll
      for (int et = 0; et < 4; et++) {
        fx4 cur = *(const fx4*)(op + et * 16);
        cur += oacc[et] * inv;
        *(fx4*)(op + et * 16) = cur;
      }
    }
  }
}

extern "C" void kernel_launch(void* const* d_in, const int* in_sizes, int n_in,
                              void* d_out, int out_size, void* d_ws, size_t ws_size,
                              hipStream_t stream) {
  (void)in_sizes; (void)n_in; (void)out_size; (void)ws_size;
  const float* img  = (const float*)d_in[0];
  const float* Wmap = (const float*)d_in[1];
  const float* bmap = (const float*)d_in[2];
  const float* ct   = (const float*)d_in[3];
  const float* lnw  = (const float*)d_in[4];
  const float* lnb  = (const float*)d_in[5];
  const float* Wq   = (const float*)d_in[6];
  const float* bq   = (const float*)d_in[7];
  const float* Wk   = (const float*)d_in[8];
  const float* bk   = (const float*)d_in[9];
  const float* Wv   = (const float*)d_in[10];
  const float* bv   = (const float*)d_in[11];
  float* out = (float*)d_out;

  // ws layout (~113 MiB): pe | sums | sqs | mean_rstd | W_bf16 | q | k | vt
  float* pe   = (float*)d_ws;                 // 151296 f
  float* sums = pe + 151296;                  // 128 f
  float* sqs  = sums + 128;                   // 128 f
  float* mr   = sqs + 128;                    // 256 f
  unsigned short* wbf   = (unsigned short*)(mr + 256);     // 589824 u16
  unsigned short* qbuf  = wbf + 589824;                    // 19365888 u16
  unsigned short* kbuf  = qbuf + (size_t)19365888;         // 19365888 u16
  unsigned short* vtbuf = kbuf + (size_t)19365888;         // 1536*64*200 u16

  k_pe<<<591, 256, 0, stream>>>(pe, sums, sqs);
  k_cvtw<<<288, 256, 0, stream>>>(Wmap, wbf);
  k_tokens<<<dim3(6, 196), 256, 0, stream>>>(img, wbf, bmap, pe, out, sums, sqs);
  k_cls<<<128, 256, 0, stream>>>(ct, pe, out, sums, sqs);
  k_fin<<<1, 128, 0, stream>>>(sums, sqs, mr);
  k_qkv<<<dim3(197, 12), 256, 0, stream>>>(out, mr, lnw, lnb, Wq, bq, Wk, bk, Wv, bv,
                                           qbuf, kbuf, vtbuf);
  k_attn<<<1536, 256, 0, stream>>>(qbuf, kbuf, vtbuf, out);
}

// Round 4
// 457.059 us; speedup vs baseline: 1.4114x; 1.1276x over previous
//
#include <hip/hip_runtime.h>

typedef float fx4 __attribute__((ext_vector_type(4)));
typedef __bf16 bf16x8 __attribute__((ext_vector_type(8)));
typedef unsigned short ushort8 __attribute__((ext_vector_type(8)));
typedef unsigned int uint2v __attribute__((ext_vector_type(2)));
typedef unsigned int uint4v __attribute__((ext_vector_type(4)));

#define MFMA16(a, b, c) __builtin_amdgcn_mfma_f32_16x16x32_bf16((a), (b), (c), 0, 0, 0)

__device__ __forceinline__ unsigned short f2bf(float f) {
  unsigned int u = __float_as_uint(f);
  return (unsigned short)((u + 0x7FFFu + ((u >> 16) & 1u)) >> 16);
}

__device__ __forceinline__ ushort8 pack8(fx4 a, fx4 b) {
  ushort8 v;
  v[0] = f2bf(a[0]); v[1] = f2bf(a[1]); v[2] = f2bf(a[2]); v[3] = f2bf(a[3]);
  v[4] = f2bf(b[0]); v[5] = f2bf(b[1]); v[6] = f2bf(b[2]); v[7] = f2bf(b[3]);
  return v;
}

// async global->LDS, 16B per lane; LDS dest is wave-uniform base, lane i lands at +16*i
__device__ __forceinline__ void gl2lds16(const unsigned short* g, void* lds_base) {
  __builtin_amdgcn_global_load_lds(
      (const __attribute__((address_space(1))) void*)(unsigned long long)(g),
      (__attribute__((address_space(3))) void*)(unsigned int)(unsigned long long)(lds_base),
      16, 0, 0);
}

// ---------- PE table + zero stats ----------
__global__ void k_pe(float* __restrict__ pe, float* __restrict__ sums, float* __restrict__ sqs) {
  int idx = blockIdx.x * 256 + threadIdx.x;  // < 197*768 = 151296 exactly
  int s = idx / 768;
  int j = idx - s * 768;
  int jj = j & ~1;
  float ang = (float)s * expf((float)jj * (-9.210340371976184f / 768.0f));
  pe[idx] = (j & 1) ? cosf(ang) : sinf(ang);
  if (blockIdx.x == 0 && threadIdx.x < 128) {
    sums[threadIdx.x] = 0.f;
    sqs[threadIdx.x] = 0.f;
  }
}

// ---------- img + W_map fp32 -> bf16 (one pass; 2048 elems/block, 9696 blocks exact) ----------
__global__ void k_cvt(const float* __restrict__ img, const float* __restrict__ W,
                      unsigned short* __restrict__ imgbf, unsigned short* __restrict__ wbf) {
  size_t i = ((size_t)blockIdx.x * 256 + threadIdx.x) * 8;
  const float* src;
  unsigned short* dst;
  if (i < 19267584) { src = img + i; dst = imgbf + i; }
  else { size_t j = i - 19267584; src = W + j; dst = wbf + j; }
  const fx4* p = (const fx4*)src;
  *(ushort8*)dst = pack8(p[0], p[1]);
}

// ---------- tokens = patches @ W_map^T + b_map + PE; also LN partial stats ----------
// grid (200 m-tiles [196 live], 6 n-tiles): bid%8 = m%8 -> same-A blocks share an XCD L2.
// m97 structure: global_load_lds width-16 into fragment-linear blobs, ds_read_b128, 16 MFMA/K-step.
__global__ __launch_bounds__(256) void k_tokens(
    const unsigned short* __restrict__ imgbf, const unsigned short* __restrict__ wbf,
    const float* __restrict__ bmap, const float* __restrict__ pe,
    float* __restrict__ out, float* __restrict__ sums, float* __restrict__ sqs) {
  __shared__ __align__(16) ushort8 Sf[16 * 64];  // blobs 0-7: A(128x32), 8-15: B(128x32)
  if (blockIdx.x >= 196) return;
  const int tid = threadIdx.x;
  const int m0 = blockIdx.x * 128;
  const int n0 = blockIdx.y * 128;
  const int lane = tid & 63;
  const int w = tid >> 6;
  const int quad = lane >> 4, l16 = lane & 15;
  const int m_off = (w & 1) * 64, n_off = (w >> 1) * 64;

  fx4 acc[4][4];
#pragma unroll
  for (int i = 0; i < 4; i++)
#pragma unroll
    for (int j = 0; j < 4; j++) acc[i][j] = (fx4){0.f, 0.f, 0.f, 0.f};

  // staging pointers: wave w loads blobs {w, 4+w} of A and {8+w, 12+w} of B.
  // blob b holds rows b*16..b*16+15 (lane&15) at cols (lane>>4)*8..+8
  const unsigned short* pA = imgbf + (size_t)(m0 + w * 16 + l16) * 768 + quad * 8;
  const unsigned short* pB = wbf + (size_t)(n0 + w * 16 + l16) * 768 + quad * 8;
  void* lA0 = (void*)&Sf[(w) * 64];
  void* lA1 = (void*)&Sf[(4 + w) * 64];
  void* lB0 = (void*)&Sf[(8 + w) * 64];
  void* lB1 = (void*)&Sf[(12 + w) * 64];

  for (int k0 = 0; k0 < 768; k0 += 32) {
    __syncthreads();
    gl2lds16(pA + k0, lA0);
    gl2lds16(pA + 64 * 768 + k0, lA1);
    gl2lds16(pB + k0, lB0);
    gl2lds16(pB + 64 * 768 + k0, lB1);
    __syncthreads();
    bf16x8 a[4], b[4];
#pragma unroll
    for (int mt = 0; mt < 4; mt++)
      a[mt] = __builtin_bit_cast(bf16x8, Sf[((w & 1) * 4 + mt) * 64 + lane]);
#pragma unroll
    for (int nt = 0; nt < 4; nt++)
      b[nt] = __builtin_bit_cast(bf16x8, Sf[(8 + (w >> 1) * 4 + nt) * 64 + lane]);
#pragma unroll
    for (int mt = 0; mt < 4; mt++)
#pragma unroll
      for (int nt = 0; nt < 4; nt++) acc[mt][nt] = MFMA16(a[mt], b[nt], acc[mt][nt]);
  }

  // epilogue: bias + PE, store tokens, accumulate LN stats (block spans <=2 samples)
  float s0 = 0.f, q0 = 0.f, s1 = 0.f, q1 = 0.f;
  const int b0 = m0 / 196;
#pragma unroll
  for (int mt = 0; mt < 4; mt++) {
#pragma unroll
    for (int nt = 0; nt < 4; nt++) {
      const int col = n0 + n_off + nt * 16 + l16;
      const float bc = bmap[col];
#pragma unroll
      for (int r = 0; r < 4; r++) {
        const int gm = m0 + m_off + mt * 16 + quad * 4 + r;
        const int bb = gm / 196;
        const int ss = gm - bb * 196 + 1;  // class token occupies s=0
        float val = acc[mt][nt][r] + bc + pe[ss * 768 + col];
        out[((size_t)bb * 197 + ss) * 768 + col] = val;
        if (bb == b0) { s0 += val; q0 += val * val; }
        else          { s1 += val; q1 += val * val; }
      }
    }
  }
  for (int off = 32; off > 0; off >>= 1) {
    s0 += __shfl_down(s0, off); q0 += __shfl_down(q0, off);
    s1 += __shfl_down(s1, off); q1 += __shfl_down(q1, off);
  }
  if (lane == 0) {
    atomicAdd(&sums[b0], s0);
    atomicAdd(&sqs[b0], q0);
    if (b0 + 1 < 128) { atomicAdd(&sums[b0 + 1], s1); atomicAdd(&sqs[b0 + 1], q1); }
  }
}

// ---------- class token row (s=0) + its stats ----------
__global__ __launch_bounds__(256) void k_cls(
    const float* __restrict__ ct, const float* __restrict__ pe,
    float* __restrict__ out, float* __restrict__ sums, float* __restrict__ sqs) {
  const int b = blockIdx.x, tid = threadIdx.x;
  float s = 0.f, q = 0.f;
#pragma unroll
  for (int it = 0; it < 3; it++) {
    int j = tid + it * 256;
    float v = ct[j] + pe[j];  // PE row 0
    out[(size_t)b * 197 * 768 + j] = v;
    s += v; q += v * v;
  }
  for (int off = 32; off > 0; off >>= 1) { s += __shfl_down(s, off); q += __shfl_down(q, off); }
  __shared__ float rs[4], rq[4];
  int w = tid >> 6;
  if ((tid & 63) == 0) { rs[w] = s; rq[w] = q; }
  __syncthreads();
  if (tid == 0) {
    atomicAdd(&sums[b], rs[0] + rs[1] + rs[2] + rs[3]);
    atomicAdd(&sqs[b], rq[0] + rq[1] + rq[2] + rq[3]);
  }
}

// ---------- finalize mean/rstd ----------
__global__ void k_fin(const float* __restrict__ sums, const float* __restrict__ sqs,
                      float* __restrict__ mr) {
  int i = threadIdx.x;  // 128
  const float inv = 1.0f / 151296.0f;
  float m = sums[i] * inv;
  float v = sqs[i] * inv - m * m;
  mr[2 * i] = m;
  mr[2 * i + 1] = rsqrtf(v + 1e-5f);
}

// ---------- QKV projection, LN fused into A/B-frag build ----------
// grid (197 m-tiles of 128 rows over M=25216, 12 heads), 256 thr; wave w: rows w*32..+32
// Q,K written [bh][s][e]; V written TRANSPOSED [bh][e][s] (stride 200) via swapped-operand
// MFMA (A=Wv, B=X_ln) whose C-layout (col=s) gives 32B-coalesced transposed stores.
__global__ __launch_bounds__(256) void k_qkv(
    const float* __restrict__ tok, const float* __restrict__ mr,
    const float* __restrict__ lnw, const float* __restrict__ lnb,
    const float* __restrict__ Wq, const float* __restrict__ bq,
    const float* __restrict__ Wk, const float* __restrict__ bk,
    const float* __restrict__ Wv, const float* __restrict__ bv,
    unsigned short* __restrict__ qob, unsigned short* __restrict__ kob,
    unsigned short* __restrict__ vtob) {
  const int tid = threadIdx.x;
  const int h = blockIdx.y;
  const int m0 = blockIdx.x * 128;
  const int lane = tid & 63, w = tid >> 6;
  const int quad = lane >> 4, l16 = lane & 15;
  const int m_base = m0 + w * 32;

  fx4 accq[2][4], acck[2][4], accv[4][2];
#pragma unroll
  for (int i = 0; i < 2; i++)
#pragma unroll
    for (int j = 0; j < 4; j++) {
      accq[i][j] = (fx4){0.f, 0.f, 0.f, 0.f};
      acck[i][j] = (fx4){0.f, 0.f, 0.f, 0.f};
      accv[j][i] = (fx4){0.f, 0.f, 0.f, 0.f};
    }

#pragma unroll
  for (int kk = 0; kk < 64; kk += 32) {
    bf16x8 a[2];  // LN'd X fragments: lane l16 = row, k = kk + quad*8 + j
#pragma unroll
    for (int mt = 0; mt < 2; mt++) {
      const int m = m_base + mt * 16 + l16;
      const int bb = m / 197;
      const int ss = m - bb * 197;
      const float mean = mr[2 * bb], rstd = mr[2 * bb + 1];
      const int cbase = h * 64 + kk + quad * 8;
      const fx4* px = (const fx4*)(tok + (size_t)m * 768 + cbase);
      const fx4* pw = (const fx4*)(lnw + (size_t)ss * 768 + cbase);
      const fx4* pb = (const fx4*)(lnb + (size_t)ss * 768 + cbase);
      fx4 y0 = (px[0] - mean) * rstd * pw[0] + pb[0];
      fx4 y1 = (px[1] - mean) * rstd * pw[1] + pb[1];
      a[mt] = __builtin_bit_cast(bf16x8, pack8(y0, y1));
    }
    // Q, K: D[m][e] = A(X) * B(W)
#pragma unroll
    for (int nt = 0; nt < 4; nt++) {
      const int n = nt * 16 + l16;
      const fx4* pq = (const fx4*)(Wq + h * 4096 + n * 64 + kk + quad * 8);
      bf16x8 bfq = __builtin_bit_cast(bf16x8, pack8(pq[0], pq[1]));
      accq[0][nt] = MFMA16(a[0], bfq, accq[0][nt]);
      accq[1][nt] = MFMA16(a[1], bfq, accq[1][nt]);
      const fx4* pk = (const fx4*)(Wk + h * 4096 + n * 64 + kk + quad * 8);
      bf16x8 bfk = __builtin_bit_cast(bf16x8, pack8(pk[0], pk[1]));
      acck[0][nt] = MFMA16(a[0], bfk, acck[0][nt]);
      acck[1][nt] = MFMA16(a[1], bfk, acck[1][nt]);
    }
    // V^T: D[e][s] = A(Wv) * B(X)
#pragma unroll
    for (int et = 0; et < 4; et++) {
      const int e = et * 16 + l16;
      const fx4* pv = (const fx4*)(Wv + h * 4096 + e * 64 + kk + quad * 8);
      bf16x8 av = __builtin_bit_cast(bf16x8, pack8(pv[0], pv[1]));
      accv[et][0] = MFMA16(av, a[0], accv[et][0]);
      accv[et][1] = MFMA16(av, a[1], accv[et][1]);
    }
  }
  // Q/K epilogue: C-layout col=e=l16, row=m=quad*4+r
#pragma unroll
  for (int mt = 0; mt < 2; mt++) {
#pragma unroll
    for (int r = 0; r < 4; r++) {
      const int m = m_base + mt * 16 + quad * 4 + r;
      const int bb = m / 197;
      const int ss = m - bb * 197;
      const size_t rowoff = (((size_t)bb * 12 + h) * 197 + ss) * 64;
#pragma unroll
      for (int nt = 0; nt < 4; nt++) {
        const int e = nt * 16 + l16;
        qob[rowoff + e] = f2bf(accq[mt][nt][r] + bq[h * 64 + e]);
        kob[rowoff + e] = f2bf(acck[mt][nt][r] + bk[h * 64 + e]);
      }
    }
  }
  // V^T epilogue: C-layout col=s=l16, row=e=quad*4+r; 16 consecutive lanes -> 32B runs
#pragma unroll
  for (int et = 0; et < 4; et++) {
#pragma unroll
    for (int r = 0; r < 4; r++) {
      const int e = et * 16 + quad * 4 + r;
      const float bvv = bv[h * 64 + e];
#pragma unroll
      for (int mt = 0; mt < 2; mt++) {
        const int m = m_base + mt * 16 + l16;
        const int bb = m / 197;
        const int ss = m - bb * 197;
        vtob[((size_t)(bb * 12 + h) * 64 + e) * 200 + ss] = f2bf(accv[et][mt][r] + bvv);
      }
    }
  }
}

// ---------- attention per (b,h), S^T formulation ----------
// K and V^T staged ONCE per block into fragment-linear LDS (base + lane*16B blobs,
// conflict-free ds_read_b128). P never touches LDS: the C-layout -> B-frag transform
// is an intra-column quad permute done with __shfl. No barriers after staging.
__global__ __launch_bounds__(256) void k_attn(
    const unsigned short* __restrict__ qb, const unsigned short* __restrict__ kb,
    const unsigned short* __restrict__ vtb, float* __restrict__ out) {
  __shared__ __align__(16) ushort8 Kf[26 * 64];   // [nt][kk][lane] 26624 B
  __shared__ __align__(16) ushort8 Vf[28 * 64];   // [et][kk7][lane] 28672 B
  const int tid = threadIdx.x;
  const int bh = blockIdx.x;
  const int b = bh / 12;
  const int h = bh - b * 12;
  const unsigned short* Qp = qb + (size_t)bh * 197 * 64;
  const unsigned short* Kp = kb + (size_t)bh * 197 * 64;
  const unsigned short* Vtp = vtb + (size_t)bh * 64 * 200;
  const int lane = tid & 63;
  const int w = tid >> 6;
  const int quad = lane >> 4;
  const int l16 = lane & 15;

  // stage K: blob i -> (nt = i>>7, kk = (i>>6)&1, lane = i&63); row t clamped
  for (int i = tid; i < 26 * 64; i += 256) {
    const int ln = i & 63, g = i >> 6;
    const int kk = g & 1, nt = g >> 1;
    int t = nt * 16 + (ln & 15);
    t = (t < 197) ? t : 196;
    const int d0 = kk * 32 + (ln >> 4) * 8;
    Kf[i] = *(const ushort8*)(Kp + t * 64 + d0);
  }
  // stage V^T: blob i -> (et = g/7, kk = g%7, lane); t-chunks >=200 clamped (masked by P=0)
  for (int i = tid; i < 28 * 64; i += 256) {
    const int ln = i & 63, g = i >> 6;
    const int kk = g % 7, et = g / 7;
    const int e = et * 16 + (ln & 15);
    int t0 = kk * 32 + (ln >> 4) * 8;
    t0 = (t0 <= 192) ? t0 : 0;  // garbage rows multiplied by zero P entries
    Vf[i] = *(const ushort8*)(Vtp + e * 200 + t0);
  }
  __syncthreads();

  const int src0 = l16 + ((quad & 1) << 5);  // lane of quad (2q)&3, same column
  const int src1 = src0 + 16;                // lane of quad (2q+1)&3

  for (int mt = w; mt < 13; mt += 4) {  // waves independent; no barrier in loop
    int qm = mt * 16 + l16;
    qm = (qm < 197) ? qm : 196;  // clamp; masked at output
    fx4 sacc[13];
#pragma unroll
    for (int nt = 0; nt < 13; nt++) sacc[nt] = (fx4){0.f, 0.f, 0.f, 0.f};
#pragma unroll
    for (int kk = 0; kk < 2; kk++) {
      bf16x8 qf = *(const bf16x8*)(Qp + qm * 64 + kk * 32 + quad * 8);
#pragma unroll
      for (int nt = 0; nt < 13; nt++) {
        bf16x8 kf = __builtin_bit_cast(bf16x8, Kf[(nt * 2 + kk) * 64 + lane]);
        sacc[nt] = MFMA16(kf, qf, sacc[nt]);  // D[t][m]: col=m=l16, row=t=quad*4+r
      }
    }
    // softmax over t (no max-sub: |s|*0.125 small by construction)
    float sm = 0.f;
    uint2v pk[13];
#pragma unroll
    for (int nt = 0; nt < 13; nt++) {
      float p[4];
#pragma unroll
      for (int r = 0; r < 4; r++) {
        const bool valid = (nt < 12) | (quad * 4 + r < 5);  // t = nt*16+quad*4+r < 197
        p[r] = valid ? __expf(sacc[nt][r] * 0.125f) : 0.f;
        sm += p[r];
      }
      pk[nt][0] = (unsigned int)f2bf(p[0]) | ((unsigned int)f2bf(p[1]) << 16);
      pk[nt][1] = (unsigned int)f2bf(p[2]) | ((unsigned int)f2bf(p[3]) << 16);
    }
    sm += __shfl_xor(sm, 16);
    sm += __shfl_xor(sm, 32);
    const float inv = 1.0f / sm;

    fx4 oacc[4];
#pragma unroll
    for (int et = 0; et < 4; et++) oacc[et] = (fx4){0.f, 0.f, 0.f, 0.f};
#pragma unroll
    for (int kk = 0; kk < 7; kk++) {
      // assemble P B-frag: halves j=0..3 from quad (2q)&3, j=4..7 from (2q+1)&3,
      // register nt' = 2kk + (q>>1); kk=6 upper half (t>=208) is zero.
      uint4v pf;
      if (kk < 6) {
        const int nA = 2 * kk, nB = 2 * kk + 1;
#pragma unroll
        for (int d = 0; d < 2; d++) {
          int a0 = __shfl((int)pk[nA][d], src0, 64);
          int b0 = __shfl((int)pk[nB][d], src0, 64);
          pf[d] = (unsigned int)((quad < 2) ? a0 : b0);
          int a1 = __shfl((int)pk[nA][d], src1, 64);
          int b1 = __shfl((int)pk[nB][d], src1, 64);
          pf[2 + d] = (unsigned int)((quad < 2) ? a1 : b1);
        }
      } else {
#pragma unroll
        for (int d = 0; d < 2; d++) {
          int a0 = __shfl((int)pk[12][d], src0, 64);
          pf[d] = (quad < 2) ? (unsigned int)a0 : 0u;
          int a1 = __shfl((int)pk[12][d], src1, 64);
          pf[2 + d] = (quad < 2) ? (unsigned int)a1 : 0u;
        }
      }
      bf16x8 pfrag = __builtin_bit_cast(bf16x8, pf);
#pragma unroll
      for (int et = 0; et < 4; et++) {
        bf16x8 vf = __builtin_bit_cast(bf16x8, Vf[(et * 7 + kk) * 64 + lane]);
        oacc[et] = MFMA16(vf, pfrag, oacc[et]);  // D[e][m]: col=m=l16, row=e
      }
    }
    const int sg = mt * 16 + l16;
    if (sg < 197) {
      float* op = out + ((size_t)b * 197 + sg) * 768 + h * 64 + quad * 4;
#pragma unroll
      for (int et = 0; et < 4; et++) {
        fx4 cur = *(const fx4*)(op + et * 16);
        cur += oacc[et] * inv;
        *(fx4*)(op + et * 16) = cur;
      }
    }
  }
}

extern "C" void kernel_launch(void* const* d_in, const int* in_sizes, int n_in,
                              void* d_out, int out_size, void* d_ws, size_t ws_size,
                              hipStream_t stream) {
  (void)in_sizes; (void)n_in; (void)out_size; (void)ws_size;
  const float* img  = (const float*)d_in[0];
  const float* Wmap = (const float*)d_in[1];
  const float* bmap = (const float*)d_in[2];
  const float* ct   = (const float*)d_in[3];
  const float* lnw  = (const float*)d_in[4];
  const float* lnb  = (const float*)d_in[5];
  const float* Wq   = (const float*)d_in[6];
  const float* bq   = (const float*)d_in[7];
  const float* Wk   = (const float*)d_in[8];
  const float* bk   = (const float*)d_in[9];
  const float* Wv   = (const float*)d_in[10];
  const float* bv   = (const float*)d_in[11];
  float* out = (float*)d_out;

  // ws layout (~113 MiB): pe | sums | sqs | mean_rstd | W_bf16 | q | k | vt
  // imgbf (38.5 MB) ALIASES qbuf: consumed by k_tokens before k_qkv writes qbuf.
  float* pe   = (float*)d_ws;                 // 151296 f
  float* sums = pe + 151296;                  // 128 f
  float* sqs  = sums + 128;                   // 128 f
  float* mr   = sqs + 128;                    // 256 f
  unsigned short* wbf   = (unsigned short*)(mr + 256);     // 589824 u16
  unsigned short* qbuf  = wbf + 589824;                    // 19365888 u16
  unsigned short* kbuf  = qbuf + (size_t)19365888;         // 19365888 u16
  unsigned short* vtbuf = kbuf + (size_t)19365888;         // 1536*64*200 u16
  unsigned short* imgbf = qbuf;                            // 19267584 u16 (alias)

  k_pe<<<591, 256, 0, stream>>>(pe, sums, sqs);
  k_cvt<<<9696, 256, 0, stream>>>(img, Wmap, imgbf, wbf);
  k_tokens<<<dim3(200, 6), 256, 0, stream>>>(imgbf, wbf, bmap, pe, out, sums, sqs);
  k_cls<<<128, 256, 0, stream>>>(ct, pe, out, sums, sqs);
  k_fin<<<1, 128, 0, stream>>>(sums, sqs, mr);
  k_qkv<<<dim3(197, 12), 256, 0, stream>>>(out, mr, lnw, lnb, Wq, bq, Wk, bk, Wv, bv,
                                           qbuf, kbuf, vtbuf);
  k_attn<<<1536, 256, 0, stream>>>(qbuf, kbuf, vtbuf, out);
}